// Round 1
// baseline (2469.802 us; speedup 1.0000x reference)
//
#include <hip/hip_runtime.h>
#include <hip/hip_bf16.h>

// ---------------------------------------------------------------------------
// SPIntraAttModuleV5: reproduce JAX reference exactly.
//   B=4, N=4096, C=256, S=256, K=32, NSAMPLES=30, EPS=1e-8
// PRNG: JAX threefry2x32. PRNG_PARTITIONABLE=1 assumes jax_threefry_partitionable
// default-True (JAX >= 0.4.30): split is fold-like, random_bits = o0^o1 of
// threefry(key, (hi64(j)=0, lo64(j)=j)). Set to 0 for legacy semantics.
// ---------------------------------------------------------------------------

#define PRNG_PARTITIONABLE 1

#define BB 4
#define NN 4096
#define CC 256
#define SS 256
#define KKK 32
#define NSAMP 30

struct Keys30 { unsigned k0[NSAMP]; unsigned k1[NSAMP]; };

__host__ __device__ __forceinline__ void threefry2x32(unsigned k0, unsigned k1,
    unsigned x0, unsigned x1, unsigned& o0, unsigned& o1) {
  unsigned ks2 = k0 ^ k1 ^ 0x1BD11BDAu;
#define TFROT(r) { x0 += x1; x1 = (x1 << (r)) | (x1 >> (32 - (r))); x1 ^= x0; }
  x0 += k0; x1 += k1;
  TFROT(13) TFROT(15) TFROT(26) TFROT(6)
  x0 += k1;  x1 += ks2 + 1u;
  TFROT(17) TFROT(29) TFROT(16) TFROT(24)
  x0 += ks2; x1 += k0 + 2u;
  TFROT(13) TFROT(15) TFROT(26) TFROT(6)
  x0 += k0;  x1 += k1 + 3u;
  TFROT(17) TFROT(29) TFROT(16) TFROT(24)
  x0 += k1;  x1 += ks2 + 4u;
  TFROT(13) TFROT(15) TFROT(26) TFROT(6)
  x0 += ks2; x1 += k0 + 5u;
#undef TFROT
  o0 = x0; o1 = x1;
}

__device__ __forceinline__ float gumbel_from_bits(unsigned bits) {
  // jax.random.uniform(float32, minval=tiny, maxval=1): top-23 bits -> [0,1)
  float u = __uint_as_float((bits >> 9) | 0x3f800000u) - 1.0f;
  u = fmaxf(u, 1.17549435e-38f);      // lax.max(minval, u*(1-tiny)+tiny) folds to this
  return -logf(-logf(u));
}

// ---------------------------------------------------------------------------
// Kernel 1: top-32 of each amatrix row (B*S rows of N values), tie -> lower idx.
// Emits indices (int) and logw = log(value + EPS).
// ---------------------------------------------------------------------------
__global__ __launch_bounds__(256) void topk_kernel(const float* __restrict__ am,
                                                   int* __restrict__ indices,
                                                   float* __restrict__ logw) {
  __shared__ float vals[NN];
  __shared__ float wv[4];
  __shared__ int   wi[4];
  const int row = blockIdx.x;            // b*S + s
  const int tid = threadIdx.x;
  const float* src = am + (size_t)row * NN;
  for (int i = tid; i < NN; i += 256) vals[i] = src[i];
  __syncthreads();
  for (int k = 0; k < KKK; ++k) {
    float bv = -INFINITY; int bi = -1;
    #pragma unroll
    for (int j = 0; j < NN / 256; ++j) {
      int idx = tid + j * 256;
      float v = vals[idx];
      if (v > bv) { bv = v; bi = idx; }   // ascending idx scan + strict > => lowest idx on tie
    }
    #pragma unroll
    for (int off = 32; off; off >>= 1) {
      float ov = __shfl_down(bv, off);
      int   oi = __shfl_down(bi, off);
      if (ov > bv || (ov == bv && oi < bi)) { bv = ov; bi = oi; }
    }
    if ((tid & 63) == 0) { wv[tid >> 6] = bv; wi[tid >> 6] = bi; }
    __syncthreads();
    if (tid == 0) {
      bv = wv[0]; bi = wi[0];
      for (int w = 1; w < 4; ++w)
        if (wv[w] > bv || (wv[w] == bv && wi[w] < bi)) { bv = wv[w]; bi = wi[w]; }
      indices[row * KKK + k] = bi;
      logw[row * KKK + k] = logf(bv + 1e-8f);
      vals[bi] = -INFINITY;
    }
    __syncthreads();
  }
}

// ---------------------------------------------------------------------------
// Kernel 2: labels[samp][b][n] = argmax_s( log(am[b,s,n]+EPS) + gumbel )
// ---------------------------------------------------------------------------
#if PRNG_PARTITIONABLE
__global__ __launch_bounds__(256) void sample_part_kernel(
    const float* __restrict__ am, unsigned char* __restrict__ labels, Keys30 keys) {
  const int t = blockIdx.x * 256 + threadIdx.x;   // t < NSAMP*BB*NN
  const int n = t & (NN - 1);
  const int b = (t >> 12) & 3;
  const int samp = t >> 14;
  const unsigned k0 = keys.k0[samp], k1 = keys.k1[samp];
  const unsigned jbase = ((unsigned)((b << 12) + n)) << 8;   // (b*N+n)*S
  float best = -INFINITY; int bi = 0;
  for (int s = 0; s < SS; ++s) {
    float a = am[((b << 8) + s) * NN + n];
    float logit = logf(a + 1e-8f);
    unsigned o0, o1;
    threefry2x32(k0, k1, 0u, jbase + (unsigned)s, o0, o1);
    float tot = gumbel_from_bits(o0 ^ o1) + logit;
    if (tot > best) { best = tot; bi = s; }
  }
  labels[((samp << 2) + b) * NN + n] = (unsigned char)bi;
}
#else
__global__ __launch_bounds__(256) void sample_orig_kernel(
    const float* __restrict__ am, unsigned char* __restrict__ labels, Keys30 keys) {
  const int t = blockIdx.x * 256 + threadIdx.x;   // t < NSAMP*2*NN
  const int n = t & (NN - 1);
  const int bh = (t >> 12) & 1;
  const int samp = t >> 13;
  const unsigned HALF = (unsigned)(2 * NN * SS);  // 2097152 = half of B*N*S
  const unsigned k0 = keys.k0[samp], k1 = keys.k1[samp];
  const unsigned jb = ((unsigned)((bh << 12) + n)) << 8;
  float best0 = -INFINITY, best2 = -INFINITY; int bi0 = 0, bi2 = 0;
  for (int s = 0; s < SS; ++s) {
    float a0 = am[((bh << 8) + s) * NN + n];
    float a2 = am[(((bh + 2) << 8) + s) * NN + n];
    unsigned j = jb + (unsigned)s;
    unsigned o0, o1;
    threefry2x32(k0, k1, j, j + HALF, o0, o1);
    float t0 = gumbel_from_bits(o0) + logf(a0 + 1e-8f);
    float t2 = gumbel_from_bits(o1) + logf(a2 + 1e-8f);
    if (t0 > best0) { best0 = t0; bi0 = s; }
    if (t2 > best2) { best2 = t2; bi2 = s; }
  }
  labels[((samp << 2) + bh) * NN + n]     = (unsigned char)bi0;
  labels[((samp << 2) + bh + 2) * NN + n] = (unsigned char)bi2;
}
#endif

// ---------------------------------------------------------------------------
// Kernel 3: per-pixel 32-key softmax attention, averaged over 30 samples.
// Block = one (b,n) pixel, 256 threads. Keys staged in LDS per sample.
// ---------------------------------------------------------------------------
__global__ __launch_bounds__(256) void attn_kernel(
    const float* __restrict__ x, const int* __restrict__ indices,
    const float* __restrict__ logw, const unsigned char* __restrict__ labels,
    float* __restrict__ out) {
  __shared__ float xn[CC];
  __shared__ float keys[KKK][CC];
  __shared__ float sc[KKK];
  __shared__ float aw[KKK];
  __shared__ int   kidx[KKK];
  __shared__ float kbias[KKK];

  const int tid = threadIdx.x;
  // XCD-aware swizzle: xcd i handles one (b, n-half) 4MB slab of x
  const int bid = blockIdx.x;
  const int xcd = bid & 7, slot = bid >> 3;
  const int b = xcd >> 1;
  const int n = ((xcd & 1) << 11) + slot;
  const int bn = (b << 12) + n;

  xn[tid] = x[(size_t)bn * CC + tid];
  float acc = 0.0f;

  const int kk = tid >> 3, g = tid & 7;       // 8 threads per key row
  const int rot = (4 * kk + g) & 31;          // bank-stagger rotation
  const int cbase = g << 5;

  for (int samp = 0; samp < NSAMP; ++samp) {
    const int label = labels[((samp << 2) + b) * NN + n];
    if (tid < KKK) {
      int r = ((b << 8) + label) * KKK + tid;
      kidx[tid] = indices[r];
      kbias[tid] = logw[r];
    }
    __syncthreads();
    #pragma unroll 4
    for (int k = 0; k < KKK; ++k) {
      keys[k][tid] = x[(size_t)((b << 12) + kidx[k]) * CC + tid];
    }
    __syncthreads();
    // scores: 8-lane partial dot per key, rotated channel order (<=2-way LDS alias)
    float p = 0.0f;
    #pragma unroll
    for (int i = 0; i < 32; ++i) {
      int c = cbase + ((i + rot) & 31);
      p += xn[c] * keys[kk][c];
    }
    p += __shfl_down(p, 4);
    p += __shfl_down(p, 2);
    p += __shfl_down(p, 1);
    if (g == 0) sc[kk] = p * 0.0625f + kbias[kk];   // /sqrt(256) + log(w+EPS)
    __syncthreads();
    if (tid < KKK) {
      float m = -INFINITY;
      #pragma unroll
      for (int k = 0; k < KKK; ++k) m = fmaxf(m, sc[k]);
      float e = expf(sc[tid] - m);
      float ssum = e;
      #pragma unroll
      for (int off = 16; off; off >>= 1) ssum += __shfl_xor(ssum, off);
      aw[tid] = e / ssum;
    }
    __syncthreads();
    #pragma unroll 8
    for (int k = 0; k < KKK; ++k) acc += aw[k] * keys[k][tid];
    __syncthreads();   // keys reused next sample
  }
  out[(size_t)bn * CC + tid] = acc / 30.0f;
}

// ---------------------------------------------------------------------------
extern "C" void kernel_launch(void* const* d_in, const int* in_sizes, int n_in,
                              void* d_out, int out_size, void* d_ws, size_t ws_size,
                              hipStream_t stream) {
  const float* x  = (const float*)d_in[0];
  const float* am = (const float*)d_in[1];
  float* out = (float*)d_out;

  char* ws = (char*)d_ws;
  int*   indices = (int*)ws;                              // B*S*K*4   = 128 KiB
  float* logw    = (float*)(ws + 131072);                 // B*S*K*4   = 128 KiB
  unsigned char* labels = (unsigned char*)(ws + 262144);  // NS*B*N    = 480 KiB

  Keys30 keys;
#if PRNG_PARTITIONABLE
  // fold-like split: key_s = threefry((0,1), (0, s))
  for (int s = 0; s < NSAMP; ++s) {
    unsigned o0, o1;
    threefry2x32(0u, 1u, 0u, (unsigned)s, o0, o1);
    keys.k0[s] = o0; keys.k1[s] = o1;
  }
#else
  // original split: threefry((0,1), iota(60)) reshaped (30,2)
  unsigned flat[2 * NSAMP];
  for (int i = 0; i < NSAMP; ++i) {
    unsigned o0, o1;
    threefry2x32(0u, 1u, (unsigned)i, (unsigned)(NSAMP + i), o0, o1);
    flat[i] = o0; flat[NSAMP + i] = o1;
  }
  for (int s = 0; s < NSAMP; ++s) { keys.k0[s] = flat[2 * s]; keys.k1[s] = flat[2 * s + 1]; }
#endif

  topk_kernel<<<BB * SS, 256, 0, stream>>>(am, indices, logw);
#if PRNG_PARTITIONABLE
  sample_part_kernel<<<(NSAMP * BB * NN) / 256, 256, 0, stream>>>(am, labels, keys);
#else
  sample_orig_kernel<<<(NSAMP * 2 * NN) / 256, 256, 0, stream>>>(am, labels, keys);
#endif
  attn_kernel<<<BB * NN, 256, 0, stream>>>(x, indices, logw, labels, out);
}

// Round 2
// 997.960 us; speedup vs baseline: 2.4749x; 2.4749x over previous
//
#include <hip/hip_runtime.h>
#include <hip/hip_bf16.h>

// ---------------------------------------------------------------------------
// SPIntraAttModuleV5:  B=4, N=4096, C=256, S=256, K=32, NSAMPLES=30, EPS=1e-8
// Round 2: bin (pixel,sample) queries by sampled superpixel, then per-(b,s)
// fp16 MFMA attention (keys staged once per block). Output via fp32 atomics.
// PRNG identical to round-1 passing version (threefry partitionable).
// ---------------------------------------------------------------------------

#define BB 4
#define NN 4096
#define CC 256
#define SS 256
#define KKK 32
#define NSAMP 30
#define NBIN (BB*SS)            // 1024
#define TOTQ (NSAMP*BB*NN)      // 491520

typedef _Float16 half8 __attribute__((ext_vector_type(8)));
typedef _Float16 half4v __attribute__((ext_vector_type(4)));
typedef float f32x4 __attribute__((ext_vector_type(4)));

struct Keys30 { unsigned k0[NSAMP]; unsigned k1[NSAMP]; };

__host__ __device__ __forceinline__ void threefry2x32(unsigned k0, unsigned k1,
    unsigned x0, unsigned x1, unsigned& o0, unsigned& o1) {
  unsigned ks2 = k0 ^ k1 ^ 0x1BD11BDAu;
#define TFROT(r) { x0 += x1; x1 = (x1 << (r)) | (x1 >> (32 - (r))); x1 ^= x0; }
  x0 += k0; x1 += k1;
  TFROT(13) TFROT(15) TFROT(26) TFROT(6)
  x0 += k1;  x1 += ks2 + 1u;
  TFROT(17) TFROT(29) TFROT(16) TFROT(24)
  x0 += ks2; x1 += k0 + 2u;
  TFROT(13) TFROT(15) TFROT(26) TFROT(6)
  x0 += k0;  x1 += k1 + 3u;
  TFROT(17) TFROT(29) TFROT(16) TFROT(24)
  x0 += k1;  x1 += ks2 + 4u;
  TFROT(13) TFROT(15) TFROT(26) TFROT(6)
  x0 += ks2; x1 += k0 + 5u;
#undef TFROT
  o0 = x0; o1 = x1;
}

__device__ __forceinline__ float gumbel_from_bits(unsigned bits) {
  float u = __uint_as_float((bits >> 9) | 0x3f800000u) - 1.0f;
  u = fmaxf(u, 1.17549435e-38f);
  return -logf(-logf(u));
}

// ---------------------------------------------------------------------------
// logits = log(am + EPS), computed once (sample kernel re-reads it 30x)
// ---------------------------------------------------------------------------
__global__ __launch_bounds__(256) void logit_kernel(const float* __restrict__ am,
                                                    float* __restrict__ lg) {
  int i = (blockIdx.x * 256 + threadIdx.x) << 2;
  float4 v = *(const float4*)&am[i];
  float4 o;
  o.x = logf(v.x + 1e-8f); o.y = logf(v.y + 1e-8f);
  o.z = logf(v.z + 1e-8f); o.w = logf(v.w + 1e-8f);
  *(float4*)&lg[i] = o;
}

// ---------------------------------------------------------------------------
// top-32 per amatrix row; tie -> lower index (matches lax.top_k)
// ---------------------------------------------------------------------------
__global__ __launch_bounds__(256) void topk_kernel(const float* __restrict__ am,
                                                   int* __restrict__ indices,
                                                   float* __restrict__ logw) {
  __shared__ float vals[NN];
  __shared__ float wv[4];
  __shared__ int   wi[4];
  const int row = blockIdx.x;            // b*S + s
  const int tid = threadIdx.x;
  const float* src = am + (size_t)row * NN;
  for (int i = tid; i < NN; i += 256) vals[i] = src[i];
  __syncthreads();
  for (int k = 0; k < KKK; ++k) {
    float bv = -INFINITY; int bi = -1;
    #pragma unroll
    for (int j = 0; j < NN / 256; ++j) {
      int idx = tid + j * 256;
      float v = vals[idx];
      if (v > bv) { bv = v; bi = idx; }
    }
    #pragma unroll
    for (int off = 32; off; off >>= 1) {
      float ov = __shfl_down(bv, off);
      int   oi = __shfl_down(bi, off);
      if (ov > bv || (ov == bv && oi < bi)) { bv = ov; bi = oi; }
    }
    if ((tid & 63) == 0) { wv[tid >> 6] = bv; wi[tid >> 6] = bi; }
    __syncthreads();
    if (tid == 0) {
      bv = wv[0]; bi = wi[0];
      for (int w = 1; w < 4; ++w)
        if (wv[w] > bv || (wv[w] == bv && wi[w] < bi)) { bv = wv[w]; bi = wi[w]; }
      indices[row * KKK + k] = bi;
      logw[row * KKK + k] = logf(bv + 1e-8f);
      vals[bi] = -INFINITY;
    }
    __syncthreads();
  }
}

// ---------------------------------------------------------------------------
// labels[samp][b][n] = argmax_s( logits[b,s,n] + gumbel(samp,b,n,s) )
// ---------------------------------------------------------------------------
__global__ __launch_bounds__(256) void sample_part_kernel(
    const float* __restrict__ lg, unsigned char* __restrict__ labels, Keys30 keys) {
  const int t = blockIdx.x * 256 + threadIdx.x;   // t < NSAMP*BB*NN
  const int n = t & (NN - 1);
  const int b = (t >> 12) & 3;
  const int samp = t >> 14;
  const unsigned k0 = keys.k0[samp], k1 = keys.k1[samp];
  const unsigned jbase = ((unsigned)((b << 12) + n)) << 8;   // (b*N+n)*S
  float best = -INFINITY; int bi = 0;
  for (int s = 0; s < SS; ++s) {
    float logit = lg[((b << 8) + s) * NN + n];
    unsigned o0, o1;
    threefry2x32(k0, k1, 0u, jbase + (unsigned)s, o0, o1);
    float tot = gumbel_from_bits(o0 ^ o1) + logit;
    if (tot > best) { best = tot; bi = s; }
  }
  labels[((samp << 2) + b) * NN + n] = (unsigned char)bi;
}

// ---------------------------------------------------------------------------
// binning: histogram -> exclusive scan -> scatter pixel ids into bins
// ---------------------------------------------------------------------------
__global__ __launch_bounds__(256) void hist_kernel(const unsigned char* __restrict__ lbl,
                                                   int* __restrict__ hist) {
  __shared__ int h[NBIN];
  for (int i = threadIdx.x; i < NBIN; i += 256) h[i] = 0;
  __syncthreads();
  for (int e = blockIdx.x * 256 + threadIdx.x; e < TOTQ; e += gridDim.x * 256) {
    int bgrp = (e >> 12) & 3;
    atomicAdd(&h[(bgrp << 8) + lbl[e]], 1);
  }
  __syncthreads();
  for (int i = threadIdx.x; i < NBIN; i += 256) if (h[i]) atomicAdd(&hist[i], h[i]);
}

__global__ __launch_bounds__(1024) void scan_kernel(const int* __restrict__ hist,
                                                    int* __restrict__ binstart,
                                                    int* __restrict__ cursor) {
  __shared__ int a[NBIN];
  const int tid = threadIdx.x;
  const int h = hist[tid];
  a[tid] = h;
  __syncthreads();
  for (int off = 1; off < NBIN; off <<= 1) {
    int v = (tid >= off) ? a[tid - off] : 0;
    __syncthreads();
    a[tid] += v;
    __syncthreads();
  }
  int excl = a[tid] - h;
  binstart[tid] = excl;
  cursor[tid]   = excl;
}

__global__ __launch_bounds__(256) void scatter_kernel(const unsigned char* __restrict__ lbl,
                                                      int* __restrict__ cursor,
                                                      int* __restrict__ qlist) {
  for (int e = blockIdx.x * 256 + threadIdx.x; e < TOTQ; e += gridDim.x * 256) {
    int bgrp = (e >> 12) & 3;
    int bin = (bgrp << 8) + lbl[e];
    int slot = atomicAdd(&cursor[bin], 1);
    qlist[slot] = e & (NN - 1);          // pixel id n (b implicit in bin)
  }
}

// ---------------------------------------------------------------------------
// Binned MFMA attention. Block = one (b,s) bin, 256 threads = 4 waves.
// Keys (32x256) staged once (row-major swizzled + transposed copy);
// queries in 64-row chunks; per wave: 16 queries, QK^T (16 mfma) -> softmax
// in regs -> P to LDS -> PV (16 mfma) -> fp32 atomicAdd into out.
// ---------------------------------------------------------------------------
__global__ __launch_bounds__(256, 2) void attn_mfma_kernel(
    const float* __restrict__ x, const int* __restrict__ indices,
    const float* __restrict__ logw, const int* __restrict__ qlist,
    const int* __restrict__ binstart, const int* __restrict__ hist,
    float* __restrict__ out) {
  __shared__ _Float16 Qlds[64 * 256];   // swizzled: elem ^ ((row&7)<<3)
  __shared__ _Float16 Klds[32 * 256];   // swizzled
  __shared__ _Float16 KT[256 * 40];     // KT[ch][key], stride 40 halves (80B)
  __shared__ _Float16 Plds[4 * 16 * 32];
  __shared__ int   kidx_s[KKK];
  __shared__ float kbias_s[KKK];

  const int tid = threadIdx.x;
  const int b = blockIdx.x & 3;          // low bits -> XCD affinity per batch
  const int s = blockIdx.x >> 2;
  const int bin = (b << 8) + s;
  const int base = binstart[bin];
  const int cnt  = hist[bin];

  if (tid < KKK) {
    int r = bin * KKK + tid;
    kidx_s[tid]  = indices[r];
    kbias_s[tid] = logw[r];
  }
  __syncthreads();

  const int w = tid >> 6, lane = tid & 63;
  const int qr = lane & 15, kg = lane >> 4;

  // ---- stage keys: Klds (swizzled row-major) + KT (transposed) ----
  {
    const int c4 = (lane) << 2;
    #pragma unroll
    for (int p = 0; p < 8; ++p) {
      int r = (p << 2) + w;
      const float4 v = *(const float4*)&x[((size_t)((b << 12) + kidx_s[r]) << 8) + c4];
      half4v h;
      h[0] = (_Float16)v.x; h[1] = (_Float16)v.y;
      h[2] = (_Float16)v.z; h[3] = (_Float16)v.w;
      *(half4v*)&Klds[(r << 8) + (c4 ^ ((r & 7) << 3))] = h;
      KT[(c4 + 0) * 40 + r] = h[0];
      KT[(c4 + 1) * 40 + r] = h[1];
      KT[(c4 + 2) * 40 + r] = h[2];
      KT[(c4 + 3) * 40 + r] = h[3];
    }
  }

  const int nchunk = (cnt + 63) >> 6;
  for (int chk = 0; chk < nchunk; ++chk) {
    const int rmax = min(64, cnt - (chk << 6));
    __syncthreads();                        // Qlds safe to overwrite / keys ready
    // ---- stage 64 query rows (fp32 -> fp16, swizzled) ----
    {
      const int c4 = lane << 2;
      #pragma unroll
      for (int p = 0; p < 16; ++p) {
        int r = (p << 2) + w;
        int rr = min(r, rmax - 1);
        int n = qlist[base + (chk << 6) + rr];
        const float4 v = *(const float4*)&x[((size_t)((b << 12) + n) << 8) + c4];
        half4v h;
        h[0] = (_Float16)v.x; h[1] = (_Float16)v.y;
        h[2] = (_Float16)v.z; h[3] = (_Float16)v.w;
        *(half4v*)&Qlds[(r << 8) + (c4 ^ ((r & 7) << 3))] = h;
      }
    }
    __syncthreads();

    // ---- S = Q K^T / 16 + bias ----
    f32x4 acc0 = {0.f, 0.f, 0.f, 0.f}, acc1 = {0.f, 0.f, 0.f, 0.f};
    {
      const int arow = (w << 4) + qr;
      const _Float16* Arow = &Qlds[arow << 8];
      const int asz = (arow & 7) << 3;
      const _Float16* B0 = &Klds[qr << 8];
      const _Float16* B1 = &Klds[(16 + qr) << 8];
      const int bsz = (qr & 7) << 3;       // (16+qr)&7 == qr&7
      #pragma unroll
      for (int kk = 0; kk < 8; ++kk) {
        const int off = (kk << 5) + (kg << 3);
        half8 a  = *(const half8*)&Arow[off ^ asz];
        half8 b0 = *(const half8*)&B0[off ^ bsz];
        half8 b1 = *(const half8*)&B1[off ^ bsz];
        acc0 = __builtin_amdgcn_mfma_f32_16x16x32_f16(a, b0, acc0, 0, 0, 0);
        acc1 = __builtin_amdgcn_mfma_f32_16x16x32_f16(a, b1, acc1, 0, 0, 0);
      }
    }
    // ---- softmax over 32 keys per query row; P -> LDS (fp16) ----
    {
      const float b0v = kbias_s[qr], b1v = kbias_s[16 + qr];
      #pragma unroll
      for (int r = 0; r < 4; ++r) {
        float s0 = acc0[r] * 0.0625f + b0v;
        float s1 = acc1[r] * 0.0625f + b1v;
        float m = fmaxf(s0, s1);
        #pragma unroll
        for (int o = 1; o < 16; o <<= 1) m = fmaxf(m, __shfl_xor(m, o));
        float e0 = __expf(s0 - m), e1 = __expf(s1 - m);
        float sm = e0 + e1;
        #pragma unroll
        for (int o = 1; o < 16; o <<= 1) sm += __shfl_xor(sm, o);
        float inv = 1.0f / sm;
        int prow = (kg << 2) + r;
        _Float16* P = &Plds[(w << 9) + (prow << 5)];
        P[qr]      = (_Float16)(e0 * inv);
        P[16 + qr] = (_Float16)(e1 * inv);
      }
    }
    __builtin_amdgcn_wave_barrier();
    // ---- O = P K ; atomic accumulate ----
    {
      half8 a2 = *(const half8*)&Plds[(w << 9) + (qr << 5) + (kg << 3)];
      int nr[4];
      #pragma unroll
      for (int r = 0; r < 4; ++r) {
        int grow = (w << 4) + (kg << 2) + r;
        nr[r] = (grow < rmax) ? qlist[base + (chk << 6) + grow] : -1;
      }
      #pragma unroll
      for (int t = 0; t < 16; ++t) {
        half8 bb = *(const half8*)&KT[((t << 4) + qr) * 40 + (kg << 3)];
        f32x4 zero = {0.f, 0.f, 0.f, 0.f};
        f32x4 o = __builtin_amdgcn_mfma_f32_16x16x32_f16(a2, bb, zero, 0, 0, 0);
        #pragma unroll
        for (int r = 0; r < 4; ++r) {
          if (nr[r] >= 0)
            atomicAdd(&out[((size_t)((b << 12) + nr[r]) << 8) + (t << 4) + qr],
                      o[r] * (1.0f / 30.0f));
        }
      }
    }
  }
}

// ---------------------------------------------------------------------------
// workspace layout (bytes)
#define OFF_IDX   0                      // 1024*32*4  = 128K
#define OFF_LOGW  131072                 // 128K
#define OFF_LBL   262144                 // 491520
#define OFF_LOGIT 786432                 // 16 MB
#define OFF_HIST  17563648               // 4K
#define OFF_BST   17567744               // 4K
#define OFF_CUR   17571840               // 4K
#define OFF_QL    17575936               // 491520*4 = 1.875 MB  (end ~19.5 MB)

extern "C" void kernel_launch(void* const* d_in, const int* in_sizes, int n_in,
                              void* d_out, int out_size, void* d_ws, size_t ws_size,
                              hipStream_t stream) {
  const float* x  = (const float*)d_in[0];
  const float* am = (const float*)d_in[1];
  float* out = (float*)d_out;

  char* ws = (char*)d_ws;
  int*   indices = (int*)(ws + OFF_IDX);
  float* logw    = (float*)(ws + OFF_LOGW);
  unsigned char* labels = (unsigned char*)(ws + OFF_LBL);
  float* logits  = (float*)(ws + OFF_LOGIT);
  int*   hist    = (int*)(ws + OFF_HIST);
  int*   binstart= (int*)(ws + OFF_BST);
  int*   cursor  = (int*)(ws + OFF_CUR);
  int*   qlist   = (int*)(ws + OFF_QL);

  Keys30 keys;
  for (int s = 0; s < NSAMP; ++s) {
    unsigned o0, o1;
    threefry2x32(0u, 1u, 0u, (unsigned)s, o0, o1);
    keys.k0[s] = o0; keys.k1[s] = o1;
  }

  hipMemsetAsync(d_out, 0, (size_t)out_size * 4, stream);
  hipMemsetAsync(hist, 0, NBIN * 4, stream);

  logit_kernel<<<(BB * SS * NN) / (256 * 4), 256, 0, stream>>>(am, logits);
  topk_kernel<<<BB * SS, 256, 0, stream>>>(am, indices, logw);
  sample_part_kernel<<<TOTQ / 256, 256, 0, stream>>>(logits, labels, keys);
  hist_kernel<<<240, 256, 0, stream>>>(labels, hist);
  scan_kernel<<<1, 1024, 0, stream>>>(hist, binstart, cursor);
  scatter_kernel<<<240, 256, 0, stream>>>(labels, cursor, qlist);
  attn_mfma_kernel<<<NBIN, 256, 0, stream>>>(x, indices, logw, qlist, binstart,
                                             hist, out);
}